// Round 1
// 398.105 us; speedup vs baseline: 1.2245x; 1.2245x over previous
//
#include <hip/hip_runtime.h>
#include <hip/hip_bf16.h>
#include <math.h>

#define NV 50000
#define NE 600000
#define NM 100000
#define KIN 256
#define HCC 256
#define NHH 8

// parallel scan geometry: 4096 elements per block (1024 threads x int4)
#define SCAN_NB0 25   // ceil((NM+1)/4096)
#define SCAN_NB1 13   // ceil((NV+1)/4096)

typedef unsigned int u32;
typedef unsigned short u16;
typedef _Float16 f16;
typedef _Float16 v8h __attribute__((ext_vector_type(8)));
typedef _Float16 v4h __attribute__((ext_vector_type(4)));
typedef float v4f __attribute__((ext_vector_type(4)));

// ---- fp16 MFMA GEMM: X[NV,256] @ W[256,256] -> X0 fp16 ----
__global__ __launch_bounds__(256) void k_gemm_f16(const float* __restrict__ X,
                                                  const float* __restrict__ W,
                                                  f16* __restrict__ X0) {
    __shared__ __align__(16) f16 sA[64][72];
    __shared__ __align__(16) f16 sB[64][72];
    const int t = threadIdx.x;
    const int r0 = blockIdx.x * 64;
    const int c0 = blockIdx.y * 64;
    const int wave = t >> 6;
    const int lane = t & 63;
    const int quad = lane >> 4;
    const int l16 = lane & 15;
    const int wr = wave & 1;
    const int wc = wave >> 1;

    v4f acc[2][2] = {{{0.f,0.f,0.f,0.f},{0.f,0.f,0.f,0.f}},
                     {{0.f,0.f,0.f,0.f},{0.f,0.f,0.f,0.f}}};

    for (int kc = 0; kc < KIN; kc += 64) {
        __syncthreads();
        #pragma unroll
        for (int i = 0; i < 4; ++i) {
            int lin = i * 256 + t;
            int row = lin >> 4;
            int k = (lin & 15) * 4;
            int gr = r0 + row;
            float4 x = make_float4(0.f, 0.f, 0.f, 0.f);
            if (gr < NV) x = *(const float4*)(X + (size_t)gr * KIN + kc + k);
            v4h hv = { (f16)x.x, (f16)x.y, (f16)x.z, (f16)x.w };
            *(v4h*)&sA[row][k] = hv;
        }
        #pragma unroll
        for (int i = 0; i < 4; ++i) {
            int lin = i * 256 + t;
            int k = lin >> 4;
            int n = (lin & 15) * 4;
            float4 b = *(const float4*)(W + (size_t)(kc + k) * HCC + c0 + n);
            sB[n + 0][k] = (f16)b.x;
            sB[n + 1][k] = (f16)b.y;
            sB[n + 2][k] = (f16)b.z;
            sB[n + 3][k] = (f16)b.w;
        }
        __syncthreads();
        #pragma unroll
        for (int ks = 0; ks < 2; ++ks) {
            const int kb = ks * 32 + quad * 8;
            v8h a[2], b[2];
            #pragma unroll
            for (int rf = 0; rf < 2; ++rf)
                a[rf] = *(const v8h*)&sA[wr * 32 + rf * 16 + l16][kb];
            #pragma unroll
            for (int cf = 0; cf < 2; ++cf)
                b[cf] = *(const v8h*)&sB[wc * 32 + cf * 16 + l16][kb];
            #pragma unroll
            for (int rf = 0; rf < 2; ++rf)
                #pragma unroll
                for (int cf = 0; cf < 2; ++cf)
                    acc[rf][cf] = __builtin_amdgcn_mfma_f32_16x16x32_f16(a[rf], b[cf], acc[rf][cf], 0, 0, 0);
        }
    }
    #pragma unroll
    for (int rf = 0; rf < 2; ++rf)
        #pragma unroll
        for (int cf = 0; cf < 2; ++cf)
            #pragma unroll
            for (int r = 0; r < 4; ++r) {
                int grow = r0 + wr * 32 + rf * 16 + quad * 4 + r;
                if (grow < NV)
                    X0[(size_t)grow * HCC + c0 + wc * 32 + cf * 16 + l16] = (f16)acc[rf][cf][r];
            }
}

// ---------------- CSR build: histogram ----------------
__global__ __launch_bounds__(256) void k_count(const int* __restrict__ vertex,
                                               const int* __restrict__ edges,
                                               int* __restrict__ e_start,
                                               int* __restrict__ v_start) {
    int i = blockIdx.x * 256 + threadIdx.x;
    if (i >= NE) return;
    atomicAdd(e_start + edges[i] + 1, 1);
    atomicAdd(v_start + vertex[i] + 1, 1);
}

// ---------------- parallel scan pass 1: per-block inclusive scan + block sums ------
// blocks [0, SCAN_NB0) cover e_start (NM+1 elems); blocks [SCAN_NB0, +SCAN_NB1) cover
// v_start (NV+1). Each block scans 4096 elems in-place; bsum[b] = block total.
__global__ __launch_bounds__(1024) void k_scan_blk(int* __restrict__ a0,
                                                   int* __restrict__ a1,
                                                   int* __restrict__ bsum) {
    const int b = blockIdx.x;
    int* a;
    int n, base;
    if (b < SCAN_NB0) { a = a0; n = NM + 1; base = b * 4096; }
    else              { a = a1; n = NV + 1; base = (b - SCAN_NB0) * 4096; }
    const int t = threadIdx.x;
    const int lane = t & 63, w = t >> 6;
    const int i = base + t * 4;
    int4 v = make_int4(0, 0, 0, 0);
    if (i + 3 < n) v = *(const int4*)(a + i);
    else if (i < n) {
        v.x = a[i];
        if (i + 1 < n) v.y = a[i + 1];
        if (i + 2 < n) v.z = a[i + 2];
    }
    // in-thread inclusive
    v.y += v.x; v.z += v.y; v.w += v.z;
    int s = v.w;
    // wave inclusive scan of thread totals
    #pragma unroll
    for (int d = 1; d < 64; d <<= 1) {
        int x = __shfl_up(s, d, 64);
        if (lane >= d) s += x;
    }
    __shared__ int partials[16];
    __shared__ int woff[16];
    if (lane == 63) partials[w] = s;
    __syncthreads();
    if (t < 16) {
        int p = partials[t];
        int ps = p;
        #pragma unroll
        for (int d = 1; d < 16; d <<= 1) {
            int x = __shfl_up(ps, d, 64);
            if (t >= d) ps += x;
        }
        woff[t] = ps - p;
        if (t == 15) bsum[b] = ps;
    }
    __syncthreads();
    const int add = (s - v.w) + woff[w];
    v.x += add; v.y += add; v.z += add; v.w += add;
    if (i + 3 < n) *(int4*)(a + i) = v;
    else if (i < n) {
        a[i] = v.x;
        if (i + 1 < n) a[i + 1] = v.y;
        if (i + 2 < n) a[i + 2] = v.z;
    }
}

// ---------------- parallel scan pass 2: add block offsets + emit cursors -----------
// block b wave-reduces its predecessors' bsum entries (<=24 reads, L2-hot), adds the
// offset to its 4096-elem chunk, and mirrors the result into the cursor array.
__global__ __launch_bounds__(1024) void k_scan_add(int* __restrict__ a0, int* __restrict__ cur0,
                                                   int* __restrict__ a1, int* __restrict__ cur1,
                                                   const int* __restrict__ bsum) {
    const int b = blockIdx.x;
    int *a, *cur;
    int n, ncur, bs0, blocal;
    if (b < SCAN_NB0) { a = a0; cur = cur0; n = NM + 1; ncur = NM; bs0 = 0;        blocal = b; }
    else              { a = a1; cur = cur1; n = NV + 1; ncur = NV; bs0 = SCAN_NB0; blocal = b - SCAN_NB0; }
    const int t = threadIdx.x;
    const int lane = t & 63;
    int x = (lane < blocal) ? bsum[bs0 + lane] : 0;
    #pragma unroll
    for (int d = 1; d < 64; d <<= 1) x += __shfl_xor(x, d, 64);
    const int off = x;
    const int i = blocal * 4096 + t * 4;
    int4 v = make_int4(0, 0, 0, 0);
    if (i + 3 < n) {
        v = *(const int4*)(a + i);
        v.x += off; v.y += off; v.z += off; v.w += off;
        *(int4*)(a + i) = v;
    } else if (i < n) {
        v.x = a[i] + off; a[i] = v.x;
        if (i + 1 < n) { v.y = a[i + 1] + off; a[i + 1] = v.y; }
        if (i + 2 < n) { v.z = a[i + 2] + off; a[i + 2] = v.z; }
    }
    if (i + 3 < ncur) {
        *(int4*)(cur + i) = v;
    } else if (i < ncur) {
        cur[i] = v.x;
        if (i + 1 < ncur) cur[i + 1] = v.y;
        if (i + 2 < ncur) cur[i + 2] = v.z;
    }
}

// ---------------- merged CSR fill (both sides in one pass) ----------------
__global__ __launch_bounds__(256) void k_fill(const int* __restrict__ vertex,
                                              const int* __restrict__ edges,
                                              int* __restrict__ e_cursor,
                                              int* __restrict__ v_cursor,
                                              int* __restrict__ e_list,
                                              int* __restrict__ v_list) {
    int i = blockIdx.x * 256 + threadIdx.x;
    if (i >= NE) return;
    int v = vertex[i], m = edges[i];
    int se = atomicAdd(e_cursor + m, 1);
    e_list[se] = v;
    int sv = atomicAdd(v_cursor + v, 1);
    v_list[sv] = m;
}

// ---------------- per-hyperedge gather: mean of member X0 rows + alpha_e ----------------
// one wave per hyperedge; lane owns 4 channels; unroll-4 for MLP.
__global__ __launch_bounds__(256) void k_edge_gather(const int* __restrict__ e_start,
                                                     const int* __restrict__ e_list,
                                                     const f16* __restrict__ X0,
                                                     const float* __restrict__ att,
                                                     f16* __restrict__ Xe,
                                                     float* __restrict__ alpha_e) {
    int m = blockIdx.x * 4 + (threadIdx.x >> 6);
    int lane = threadIdx.x & 63;
    int s0 = e_start[m], s1 = e_start[m + 1];
    int c = lane * 4;
    float4 acc = make_float4(0.f, 0.f, 0.f, 0.f);
    int i = s0;
    for (; i + 3 < s1; i += 4) {
        int v0 = e_list[i], v1 = e_list[i + 1], v2 = e_list[i + 2], v3 = e_list[i + 3];
        v4h x0 = *(const v4h*)(X0 + (size_t)v0 * HCC + c);
        v4h x1 = *(const v4h*)(X0 + (size_t)v1 * HCC + c);
        v4h x2 = *(const v4h*)(X0 + (size_t)v2 * HCC + c);
        v4h x3 = *(const v4h*)(X0 + (size_t)v3 * HCC + c);
        acc.x += (float)x0[0] + (float)x1[0] + (float)x2[0] + (float)x3[0];
        acc.y += (float)x0[1] + (float)x1[1] + (float)x2[1] + (float)x3[1];
        acc.z += (float)x0[2] + (float)x1[2] + (float)x2[2] + (float)x3[2];
        acc.w += (float)x0[3] + (float)x1[3] + (float)x2[3] + (float)x3[3];
    }
    for (; i < s1; ++i) {
        int v0 = e_list[i];
        v4h x0 = *(const v4h*)(X0 + (size_t)v0 * HCC + c);
        acc.x += (float)x0[0];
        acc.y += (float)x0[1];
        acc.z += (float)x0[2];
        acc.w += (float)x0[3];
    }
    float inv = 1.0f / fmaxf((float)(s1 - s0), 1.0f);
    acc.x *= inv; acc.y *= inv; acc.z *= inv; acc.w *= inv;
    v4h xev = { (f16)acc.x, (f16)acc.y, (f16)acc.z, (f16)acc.w };
    *(v4h*)(Xe + (size_t)m * HCC + c) = xev;
    float4 av = *(const float4*)(att + c);
    float p = acc.x * av.x + acc.y * av.y + acc.z * av.z + acc.w * av.w;
    p += __shfl_xor(p, 1, 64);
    p += __shfl_xor(p, 2, 64);
    p += __shfl_xor(p, 4, 64);
    if ((lane & 7) == 0) alpha_e[m * NHH + (lane >> 3)] = p;
}

// ---------------- per-vertex gather: softmax (no max shift; |alpha|<~2) + GELU ----------
// exp(a)/sum(exp(a)) == exp(a-max)/sum(exp(a-max)) exactly; overflow impossible
// since std(alpha)~0.25. Single pass, unroll-2 for two gather chains in flight.
__global__ __launch_bounds__(256) void k_vertex_gather(const int* __restrict__ v_start,
                                                       const int* __restrict__ v_list,
                                                       const f16* __restrict__ Xe,
                                                       const float* __restrict__ alpha_e,
                                                       float* __restrict__ out) {
    int v = blockIdx.x * 4 + (threadIdx.x >> 6);
    int lane = threadIdx.x & 63;
    int s0 = v_start[v], s1 = v_start[v + 1];
    int h = lane >> 3;
    int c = lane * 4;
    float4 acc = make_float4(0.f, 0.f, 0.f, 0.f);
    float se = 0.f;
    int i = s0;
    for (; i + 1 < s1; i += 2) {
        int m0 = v_list[i], m1 = v_list[i + 1];
        float a0 = alpha_e[m0 * NHH + h];
        float a1 = alpha_e[m1 * NHH + h];
        v4h x0 = *(const v4h*)(Xe + (size_t)m0 * HCC + c);
        v4h x1 = *(const v4h*)(Xe + (size_t)m1 * HCC + c);
        a0 = (a0 >= 0.f) ? a0 : 0.2f * a0;
        a1 = (a1 >= 0.f) ? a1 : 0.2f * a1;
        float e0 = __expf(a0);
        float e1 = __expf(a1);
        acc.x += e0 * (float)x0[0] + e1 * (float)x1[0];
        acc.y += e0 * (float)x0[1] + e1 * (float)x1[1];
        acc.z += e0 * (float)x0[2] + e1 * (float)x1[2];
        acc.w += e0 * (float)x0[3] + e1 * (float)x1[3];
        se += e0 + e1;
    }
    if (i < s1) {
        int m0 = v_list[i];
        float a0 = alpha_e[m0 * NHH + h];
        v4h x0 = *(const v4h*)(Xe + (size_t)m0 * HCC + c);
        a0 = (a0 >= 0.f) ? a0 : 0.2f * a0;
        float e0 = __expf(a0);
        acc.x += e0 * (float)x0[0];
        acc.y += e0 * (float)x0[1];
        acc.z += e0 * (float)x0[2];
        acc.w += e0 * (float)x0[3];
        se += e0;
    }
    float inv = 1.0f / (se + 1e-16f);
    float4 o;
    float xx;
    xx = acc.x * inv; o.x = 0.5f * xx * (1.f + erff(xx * 0.70710678118f));
    xx = acc.y * inv; o.y = 0.5f * xx * (1.f + erff(xx * 0.70710678118f));
    xx = acc.z * inv; o.z = 0.5f * xx * (1.f + erff(xx * 0.70710678118f));
    xx = acc.w * inv; o.w = 0.5f * xx * (1.f + erff(xx * 0.70710678118f));
    *(float4*)(out + (size_t)v * HCC + c) = o;
}

extern "C" void kernel_launch(void* const* d_in, const int* in_sizes, int n_in,
                              void* d_out, int out_size, void* d_ws, size_t ws_size,
                              hipStream_t stream) {
    const float* X = (const float*)d_in[0];    // [NV, 256] fp32
    const float* W = (const float*)d_in[1];    // [256, 256] fp32
    const float* att = (const float*)d_in[2];  // [256] fp32
    const int* vertex = (const int*)d_in[3];   // [NE] int32
    const int* edges = (const int*)d_in[4];    // [NE] int32
    float* out = (float*)d_out;                // [NV*256] fp32

    char* ws = (char*)d_ws;
    size_t off = 0;
    // all allocations padded to 16B so scan/cursor kernels can use int4
    #define WS_TAKE(bytes) (ws + off); off += (((size_t)(bytes)) + 15) & ~(size_t)15
    f16* X0 = (f16*)WS_TAKE((size_t)NV * HCC * 2);      // 25.6MB
    f16* Xe = (f16*)WS_TAKE((size_t)NM * HCC * 2);      // 51.2MB
    float* alpha_e = (float*)WS_TAKE((size_t)NM * NHH * 4); // 3.2MB
    int* e_start = (int*)WS_TAKE((size_t)(NM + 1) * 4);
    int* v_start = (int*)WS_TAKE((size_t)(NV + 1) * 4);
    int* e_list = (int*)WS_TAKE((size_t)NE * 4);        // 2.4MB
    int* v_list = (int*)WS_TAKE((size_t)NE * 4);        // 2.4MB
    int* e_cursor = (int*)WS_TAKE((size_t)NM * 4);
    int* v_cursor = (int*)WS_TAKE((size_t)NV * 4);
    int* bsum = (int*)WS_TAKE(64 * 4);                  // 38 used
    #undef WS_TAKE

    // zero histograms (e_start .. v_start contiguous incl. padding)
    size_t hist_bytes = (((size_t)(NM + 1) * 4 + 15) & ~(size_t)15) +
                        (((size_t)(NV + 1) * 4 + 15) & ~(size_t)15);
    hipMemsetAsync(e_start, 0, hist_bytes, stream);

    const int EB = (NE + 255) / 256;
    k_count<<<EB, 256, 0, stream>>>(vertex, edges, e_start, v_start);
    k_scan_blk<<<SCAN_NB0 + SCAN_NB1, 1024, 0, stream>>>(e_start, v_start, bsum);
    k_scan_add<<<SCAN_NB0 + SCAN_NB1, 1024, 0, stream>>>(e_start, e_cursor, v_start, v_cursor, bsum);
    k_fill<<<EB, 256, 0, stream>>>(vertex, edges, e_cursor, v_cursor, e_list, v_list);
    dim3 ggrid((NV + 63) / 64, HCC / 64);
    k_gemm_f16<<<ggrid, 256, 0, stream>>>(X, W, X0);
    k_edge_gather<<<NM / 4, 256, 0, stream>>>(e_start, e_list, X0, att, Xe, alpha_e);
    k_vertex_gather<<<NV / 4, 256, 0, stream>>>(v_start, v_list, Xe, alpha_e, out);
}

// Round 2
// 318.757 us; speedup vs baseline: 1.5293x; 1.2489x over previous
//
#include <hip/hip_runtime.h>
#include <hip/hip_bf16.h>
#include <math.h>

#define NV 50000
#define NE 600000
#define NM 100000
#define KIN 256
#define HCC 256
#define NHH 8

// parallel scan geometry: 4096 elements per block (1024 threads x int4)
#define SCAN_NB0 25   // ceil((NM+1)/4096)
#define SCAN_NB1 13   // ceil((NV+1)/4096)

#define CNT_B 2344    // ceil(NE/256) incidence blocks
#define GEMM_BX 782   // ceil(NV/64)
#define GEMM_B (GEMM_BX * 4)

typedef unsigned int u32;
typedef unsigned short u16;
typedef _Float16 f16;
typedef _Float16 v8h __attribute__((ext_vector_type(8)));
typedef _Float16 v4h __attribute__((ext_vector_type(4)));
typedef float v4f __attribute__((ext_vector_type(4)));

// ---- fused: incidence count+rank (atomic) blocks || fp16 MFMA GEMM blocks ----
// blocks [0, CNT_B): r_e[i]/r_v[i] = rank of incidence i within its edge/vertex
// segment (atomicAdd return), hist[seg+1]++ for the scan.
// blocks [CNT_B, CNT_B+GEMM_B): X0 = f16(X @ W), 64x64 tiles.
// Independent roles: count is atomic-latency-bound (VALU ~0%), GEMM is MFMA-bound;
// fusing hides the GEMM under the atomic pass.
__global__ __launch_bounds__(256) void k_count_gemm(const int* __restrict__ vertex,
                                                    const int* __restrict__ edges,
                                                    int* __restrict__ e_hist,
                                                    int* __restrict__ v_hist,
                                                    u16* __restrict__ r_e,
                                                    u16* __restrict__ r_v,
                                                    const float* __restrict__ X,
                                                    const float* __restrict__ W,
                                                    f16* __restrict__ X0) {
    __shared__ __align__(16) f16 sA[64][72];
    __shared__ __align__(16) f16 sB[64][72];
    const int bid = blockIdx.x;
    const int t = threadIdx.x;
    if (bid < CNT_B) {
        int i = bid * 256 + t;
        if (i < NE) {
            int v = vertex[i], m = edges[i];
            r_e[i] = (u16)atomicAdd(e_hist + m + 1, 1);
            r_v[i] = (u16)atomicAdd(v_hist + v + 1, 1);
        }
        return;
    }
    const int g = bid - CNT_B;
    const int r0 = (g >> 2) * 64;
    const int c0 = (g & 3) * 64;
    const int wave = t >> 6;
    const int lane = t & 63;
    const int quad = lane >> 4;
    const int l16 = lane & 15;
    const int wr = wave & 1;
    const int wc = wave >> 1;

    v4f acc[2][2] = {{{0.f,0.f,0.f,0.f},{0.f,0.f,0.f,0.f}},
                     {{0.f,0.f,0.f,0.f},{0.f,0.f,0.f,0.f}}};

    for (int kc = 0; kc < KIN; kc += 64) {
        __syncthreads();
        #pragma unroll
        for (int i = 0; i < 4; ++i) {
            int lin = i * 256 + t;
            int row = lin >> 4;
            int k = (lin & 15) * 4;
            int gr = r0 + row;
            float4 x = make_float4(0.f, 0.f, 0.f, 0.f);
            if (gr < NV) x = *(const float4*)(X + (size_t)gr * KIN + kc + k);
            v4h hv = { (f16)x.x, (f16)x.y, (f16)x.z, (f16)x.w };
            *(v4h*)&sA[row][k] = hv;
        }
        #pragma unroll
        for (int i = 0; i < 4; ++i) {
            int lin = i * 256 + t;
            int k = lin >> 4;
            int n = (lin & 15) * 4;
            float4 b = *(const float4*)(W + (size_t)(kc + k) * HCC + c0 + n);
            sB[n + 0][k] = (f16)b.x;
            sB[n + 1][k] = (f16)b.y;
            sB[n + 2][k] = (f16)b.z;
            sB[n + 3][k] = (f16)b.w;
        }
        __syncthreads();
        #pragma unroll
        for (int ks = 0; ks < 2; ++ks) {
            const int kb = ks * 32 + quad * 8;
            v8h a[2], b[2];
            #pragma unroll
            for (int rf = 0; rf < 2; ++rf)
                a[rf] = *(const v8h*)&sA[wr * 32 + rf * 16 + l16][kb];
            #pragma unroll
            for (int cf = 0; cf < 2; ++cf)
                b[cf] = *(const v8h*)&sB[wc * 32 + cf * 16 + l16][kb];
            #pragma unroll
            for (int rf = 0; rf < 2; ++rf)
                #pragma unroll
                for (int cf = 0; cf < 2; ++cf)
                    acc[rf][cf] = __builtin_amdgcn_mfma_f32_16x16x32_f16(a[rf], b[cf], acc[rf][cf], 0, 0, 0);
        }
    }
    #pragma unroll
    for (int rf = 0; rf < 2; ++rf)
        #pragma unroll
        for (int cf = 0; cf < 2; ++cf)
            #pragma unroll
            for (int r = 0; r < 4; ++r) {
                int grow = r0 + wr * 32 + rf * 16 + quad * 4 + r;
                if (grow < NV)
                    X0[(size_t)grow * HCC + c0 + wc * 32 + cf * 16 + l16] = (f16)acc[rf][cf][r];
            }
}

// ---------------- parallel scan pass 1: per-block inclusive scan + block sums ------
__global__ __launch_bounds__(1024) void k_scan_blk(int* __restrict__ a0,
                                                   int* __restrict__ a1,
                                                   int* __restrict__ bsum) {
    const int b = blockIdx.x;
    int* a;
    int n, base;
    if (b < SCAN_NB0) { a = a0; n = NM + 1; base = b * 4096; }
    else              { a = a1; n = NV + 1; base = (b - SCAN_NB0) * 4096; }
    const int t = threadIdx.x;
    const int lane = t & 63, w = t >> 6;
    const int i = base + t * 4;
    int4 v = make_int4(0, 0, 0, 0);
    if (i + 3 < n) v = *(const int4*)(a + i);
    else if (i < n) {
        v.x = a[i];
        if (i + 1 < n) v.y = a[i + 1];
        if (i + 2 < n) v.z = a[i + 2];
    }
    v.y += v.x; v.z += v.y; v.w += v.z;
    int s = v.w;
    #pragma unroll
    for (int d = 1; d < 64; d <<= 1) {
        int x = __shfl_up(s, d, 64);
        if (lane >= d) s += x;
    }
    __shared__ int partials[16];
    __shared__ int woff[16];
    if (lane == 63) partials[w] = s;
    __syncthreads();
    if (t < 16) {
        int p = partials[t];
        int ps = p;
        #pragma unroll
        for (int d = 1; d < 16; d <<= 1) {
            int x = __shfl_up(ps, d, 64);
            if (t >= d) ps += x;
        }
        woff[t] = ps - p;
        if (t == 15) bsum[b] = ps;
    }
    __syncthreads();
    const int add = (s - v.w) + woff[w];
    v.x += add; v.y += add; v.z += add; v.w += add;
    if (i + 3 < n) *(int4*)(a + i) = v;
    else if (i < n) {
        a[i] = v.x;
        if (i + 1 < n) a[i + 1] = v.y;
        if (i + 2 < n) a[i + 2] = v.z;
    }
}

// ---------------- parallel scan pass 2: add block offsets (no cursor mirror) -------
__global__ __launch_bounds__(1024) void k_scan_add(int* __restrict__ a0,
                                                   int* __restrict__ a1,
                                                   const int* __restrict__ bsum) {
    const int b = blockIdx.x;
    int* a;
    int n, bs0, blocal;
    if (b < SCAN_NB0) { a = a0; n = NM + 1; bs0 = 0;        blocal = b; }
    else              { a = a1; n = NV + 1; bs0 = SCAN_NB0; blocal = b - SCAN_NB0; }
    const int t = threadIdx.x;
    const int lane = t & 63;
    int x = (lane < blocal) ? bsum[bs0 + lane] : 0;
    #pragma unroll
    for (int d = 1; d < 64; d <<= 1) x += __shfl_xor(x, d, 64);
    const int off = x;
    if (off == 0 && blocal == 0) { /* still fall through for uniformity */ }
    const int i = blocal * 4096 + t * 4;
    if (i + 3 < n) {
        int4 v = *(const int4*)(a + i);
        v.x += off; v.y += off; v.z += off; v.w += off;
        *(int4*)(a + i) = v;
    } else if (i < n) {
        a[i] += off;
        if (i + 1 < n) a[i + 1] += off;
        if (i + 2 < n) a[i + 2] += off;
    }
}

// ---------------- e-side CSR fill: atomic-free (rank recorded in count pass) -------
__global__ __launch_bounds__(256) void k_efill(const int* __restrict__ vertex,
                                               const int* __restrict__ edges,
                                               const u16* __restrict__ r_e,
                                               const int* __restrict__ e_start,
                                               int* __restrict__ e_list) {
    int i = blockIdx.x * 256 + threadIdx.x;
    if (i >= NE) return;
    int m = edges[i];
    e_list[e_start[m] + (int)r_e[i]] = vertex[i];
}

// ---- fused: v-side CSR fill (atomic-free) blocks || per-hyperedge gather blocks ----
// blocks [0, CNT_B): v_list scatter (independent of e_list / X0).
// blocks [CNT_B, CNT_B + NM/4): mean of member X0 rows + alpha_e; one wave per
// hyperedge, lane owns 4 channels.
__global__ __launch_bounds__(256) void k_vfill_egather(const int* __restrict__ vertex,
                                                       const int* __restrict__ edges,
                                                       const u16* __restrict__ r_v,
                                                       const int* __restrict__ v_start,
                                                       int* __restrict__ v_list,
                                                       const int* __restrict__ e_start,
                                                       const int* __restrict__ e_list,
                                                       const f16* __restrict__ X0,
                                                       const float* __restrict__ att,
                                                       f16* __restrict__ Xe,
                                                       float* __restrict__ alpha_e) {
    const int bid = blockIdx.x;
    if (bid < CNT_B) {
        int i = bid * 256 + threadIdx.x;
        if (i < NE) {
            int v = vertex[i];
            v_list[v_start[v] + (int)r_v[i]] = edges[i];
        }
        return;
    }
    int m = (bid - CNT_B) * 4 + (threadIdx.x >> 6);
    int lane = threadIdx.x & 63;
    int s0 = e_start[m], s1 = e_start[m + 1];
    int c = lane * 4;
    float4 acc = make_float4(0.f, 0.f, 0.f, 0.f);
    int i = s0;
    for (; i + 3 < s1; i += 4) {
        int v0 = e_list[i], v1 = e_list[i + 1], v2 = e_list[i + 2], v3 = e_list[i + 3];
        v4h x0 = *(const v4h*)(X0 + (size_t)v0 * HCC + c);
        v4h x1 = *(const v4h*)(X0 + (size_t)v1 * HCC + c);
        v4h x2 = *(const v4h*)(X0 + (size_t)v2 * HCC + c);
        v4h x3 = *(const v4h*)(X0 + (size_t)v3 * HCC + c);
        acc.x += (float)x0[0] + (float)x1[0] + (float)x2[0] + (float)x3[0];
        acc.y += (float)x0[1] + (float)x1[1] + (float)x2[1] + (float)x3[1];
        acc.z += (float)x0[2] + (float)x1[2] + (float)x2[2] + (float)x3[2];
        acc.w += (float)x0[3] + (float)x1[3] + (float)x2[3] + (float)x3[3];
    }
    for (; i < s1; ++i) {
        int v0 = e_list[i];
        v4h x0 = *(const v4h*)(X0 + (size_t)v0 * HCC + c);
        acc.x += (float)x0[0];
        acc.y += (float)x0[1];
        acc.z += (float)x0[2];
        acc.w += (float)x0[3];
    }
    float inv = 1.0f / fmaxf((float)(s1 - s0), 1.0f);
    acc.x *= inv; acc.y *= inv; acc.z *= inv; acc.w *= inv;
    v4h xev = { (f16)acc.x, (f16)acc.y, (f16)acc.z, (f16)acc.w };
    *(v4h*)(Xe + (size_t)m * HCC + c) = xev;
    float4 av = *(const float4*)(att + c);
    float p = acc.x * av.x + acc.y * av.y + acc.z * av.z + acc.w * av.w;
    p += __shfl_xor(p, 1, 64);
    p += __shfl_xor(p, 2, 64);
    p += __shfl_xor(p, 4, 64);
    if ((lane & 7) == 0) alpha_e[m * NHH + (lane >> 3)] = p;
}

// ---------------- per-vertex gather: softmax (no max shift; |alpha|<~2) + GELU ----------
__global__ __launch_bounds__(256) void k_vertex_gather(const int* __restrict__ v_start,
                                                       const int* __restrict__ v_list,
                                                       const f16* __restrict__ Xe,
                                                       const float* __restrict__ alpha_e,
                                                       float* __restrict__ out) {
    int v = blockIdx.x * 4 + (threadIdx.x >> 6);
    int lane = threadIdx.x & 63;
    int s0 = v_start[v], s1 = v_start[v + 1];
    int h = lane >> 3;
    int c = lane * 4;
    float4 acc = make_float4(0.f, 0.f, 0.f, 0.f);
    float se = 0.f;
    int i = s0;
    for (; i + 1 < s1; i += 2) {
        int m0 = v_list[i], m1 = v_list[i + 1];
        float a0 = alpha_e[m0 * NHH + h];
        float a1 = alpha_e[m1 * NHH + h];
        v4h x0 = *(const v4h*)(Xe + (size_t)m0 * HCC + c);
        v4h x1 = *(const v4h*)(Xe + (size_t)m1 * HCC + c);
        a0 = (a0 >= 0.f) ? a0 : 0.2f * a0;
        a1 = (a1 >= 0.f) ? a1 : 0.2f * a1;
        float e0 = __expf(a0);
        float e1 = __expf(a1);
        acc.x += e0 * (float)x0[0] + e1 * (float)x1[0];
        acc.y += e0 * (float)x0[1] + e1 * (float)x1[1];
        acc.z += e0 * (float)x0[2] + e1 * (float)x1[2];
        acc.w += e0 * (float)x0[3] + e1 * (float)x1[3];
        se += e0 + e1;
    }
    if (i < s1) {
        int m0 = v_list[i];
        float a0 = alpha_e[m0 * NHH + h];
        v4h x0 = *(const v4h*)(Xe + (size_t)m0 * HCC + c);
        a0 = (a0 >= 0.f) ? a0 : 0.2f * a0;
        float e0 = __expf(a0);
        acc.x += e0 * (float)x0[0];
        acc.y += e0 * (float)x0[1];
        acc.z += e0 * (float)x0[2];
        acc.w += e0 * (float)x0[3];
        se += e0;
    }
    float inv = 1.0f / (se + 1e-16f);
    float4 o;
    float xx;
    xx = acc.x * inv; o.x = 0.5f * xx * (1.f + erff(xx * 0.70710678118f));
    xx = acc.y * inv; o.y = 0.5f * xx * (1.f + erff(xx * 0.70710678118f));
    xx = acc.z * inv; o.z = 0.5f * xx * (1.f + erff(xx * 0.70710678118f));
    xx = acc.w * inv; o.w = 0.5f * xx * (1.f + erff(xx * 0.70710678118f));
    *(float4*)(out + (size_t)v * HCC + c) = o;
}

extern "C" void kernel_launch(void* const* d_in, const int* in_sizes, int n_in,
                              void* d_out, int out_size, void* d_ws, size_t ws_size,
                              hipStream_t stream) {
    const float* X = (const float*)d_in[0];    // [NV, 256] fp32
    const float* W = (const float*)d_in[1];    // [256, 256] fp32
    const float* att = (const float*)d_in[2];  // [256] fp32
    const int* vertex = (const int*)d_in[3];   // [NE] int32
    const int* edges = (const int*)d_in[4];    // [NE] int32
    float* out = (float*)d_out;                // [NV*256] fp32

    char* ws = (char*)d_ws;
    size_t off = 0;
    // all allocations padded to 16B so scan kernels can use int4
    #define WS_TAKE(bytes) (ws + off); off += (((size_t)(bytes)) + 15) & ~(size_t)15
    f16* X0 = (f16*)WS_TAKE((size_t)NV * HCC * 2);          // 25.6MB
    f16* Xe = (f16*)WS_TAKE((size_t)NM * HCC * 2);          // 51.2MB
    float* alpha_e = (float*)WS_TAKE((size_t)NM * NHH * 4); // 3.2MB
    int* e_start = (int*)WS_TAKE((size_t)(NM + 1) * 4);
    int* v_start = (int*)WS_TAKE((size_t)(NV + 1) * 4);
    int* e_list = (int*)WS_TAKE((size_t)NE * 4);            // 2.4MB
    int* v_list = (int*)WS_TAKE((size_t)NE * 4);            // 2.4MB
    u16* r_e = (u16*)WS_TAKE((size_t)NE * 2);               // 1.2MB rank-in-edge
    u16* r_v = (u16*)WS_TAKE((size_t)NE * 2);               // 1.2MB rank-in-vertex
    int* bsum = (int*)WS_TAKE(64 * 4);                      // 38 used
    #undef WS_TAKE

    // zero histograms (e_start .. v_start contiguous incl. padding)
    size_t hist_bytes = (((size_t)(NM + 1) * 4 + 15) & ~(size_t)15) +
                        (((size_t)(NV + 1) * 4 + 15) & ~(size_t)15);
    hipMemsetAsync(e_start, 0, hist_bytes, stream);

    k_count_gemm<<<CNT_B + GEMM_B, 256, 0, stream>>>(vertex, edges, e_start, v_start,
                                                     r_e, r_v, X, W, X0);
    k_scan_blk<<<SCAN_NB0 + SCAN_NB1, 1024, 0, stream>>>(e_start, v_start, bsum);
    k_scan_add<<<SCAN_NB0 + SCAN_NB1, 1024, 0, stream>>>(e_start, v_start, bsum);
    k_efill<<<CNT_B, 256, 0, stream>>>(vertex, edges, r_e, e_start, e_list);
    k_vfill_egather<<<CNT_B + NM / 4, 256, 0, stream>>>(vertex, edges, r_v, v_start, v_list,
                                                        e_start, e_list, X0, att, Xe, alpha_e);
    k_vertex_gather<<<NV / 4, 256, 0, stream>>>(v_start, v_list, Xe, alpha_e, out);
}